// Round 11
// baseline (257.270 us; speedup 1.0000x reference)
//
#include <hip/hip_runtime.h>

typedef unsigned short u16;
typedef unsigned int u32;
typedef __attribute__((ext_vector_type(8))) short bf16x8;
typedef __attribute__((ext_vector_type(4))) float f32x4;

#define LSEQ 1024

__device__ __forceinline__ float b2f(u16 v) { return __uint_as_float(((u32)v) << 16); }
__device__ __forceinline__ u16 f2b(float f) {
    u32 x = __float_as_uint(f);
    return (u16)((x + 0x7fffu + ((x >> 16) & 1u)) >> 16);
}
__device__ __forceinline__ float rdf(const void* p, size_t i, int f) {
    return f ? b2f(((const u16*)p)[i]) : ((const float*)p)[i];
}
__device__ __forceinline__ float fsig(float x) {
    return __builtin_amdgcn_rcpf(1.f + __expf(-x));
}

typedef const __attribute__((address_space(1))) u32* gp_t;
typedef __attribute__((address_space(3))) u32* lp_t;
__device__ __forceinline__ void gload16(const u16* g, u16* lds_wave_base) {
    __builtin_amdgcn_global_load_lds((gp_t)g, (lp_t)lds_wave_base, 16, 0, 0);
}

// ---------------- prep: per-block dtype detect + x->bf16 + all weight transposes ----------------
__global__ __launch_bounds__(256) void prep_k(const void* __restrict__ x,
                                              const void* __restrict__ W_in,
                                              const void* __restrict__ W_out,
                                              const void* __restrict__ W_x,
                                              const void* __restrict__ W_dt,
                                              u16* __restrict__ xb,
                                              u16* __restrict__ W_in_t,
                                              u16* __restrict__ W_out_t,
                                              u16* __restrict__ W_x_t,
                                              u16* __restrict__ W_dt_t,
                                              int* __restrict__ flag) {
    __shared__ int cnt;
    __shared__ u16 tile[32][33];
    if (threadIdx.x == 0) cnt = 0;
    __syncthreads();
    const u16* xu = (const u16*)x;
    int c = 0;
#pragma unroll
    for (int j = 0; j < 8; ++j) {
        u16 u = xu[threadIdx.x * 8 + j];
        int e = (u >> 7) & 0xFF;
        c += (e == 0 || (e >= 100 && e <= 140)) ? 1 : 0;
    }
    atomicAdd(&cnt, c);
    __syncthreads();
    const int f = (cnt >= 1638) ? 1 : 0;
    if (blockIdx.x == 0 && threadIdx.x == 0) *flag = f;

    int blk = blockIdx.x;
    if (blk < 4096) {  // x -> bf16
        int i = blk * 256 + threadIdx.x;
        xb[i] = f ? xu[i] : f2b(((const float*)x)[i]);
        return;
    }
    blk -= 4096;
    // weight transposes: dst[Cp,R] = src[R,Cn]^T (zero-padded rows >= Cn)
    const void* src; u16* dst; int R, Cn, nbc, t;
    if (blk < 4096)      { src = W_in;  dst = W_in_t;  R = 1024; Cn = 4096; nbc = 128; t = blk; }
    else if (blk < 6144) { src = W_out; dst = W_out_t; R = 2048; Cn = 1024; nbc = 32;  t = blk - 4096; }
    else if (blk < 6400) { src = W_x;   dst = W_x_t;   R = 2048; Cn = 96;   nbc = 4;   t = blk - 6144; }
    else                 { src = W_dt;  dst = W_dt_t;  R = 64;   Cn = 2048; nbc = 64;  t = blk - 6400; }
    int br = t / nbc, bc = t - br * nbc;
    int r0 = br * 32, c0 = bc * 32;
    int tx = threadIdx.x & 31, ty0 = threadIdx.x >> 5;
#pragma unroll
    for (int p = 0; p < 4; ++p) {
        int ty = ty0 + p * 8;
        float v = (c0 + tx < Cn) ? rdf(src, (size_t)(r0 + ty) * Cn + c0 + tx, f) : 0.f;
        tile[ty][tx] = f2b(v);
    }
    __syncthreads();
#pragma unroll
    for (int p = 0; p < 4; ++p) {
        int ty = ty0 + p * 8;
        dst[(size_t)(c0 + ty) * R + r0 + tx] = tile[tx][ty];
    }
}

// ---------------- GEMM, B transposed: C[M,N] = A[M,K] * Bt[N,K]^T ----------------
// OUT_MODE: 1=bf16, 2=dual(flag), 4=softplus(v+bias[col]) fp32,
//           5=fp32 partial at C + blockIdx.z*M*N (K split into kslices)
template <int MT, int NT, int OUT_MODE>
__global__ __launch_bounds__(256) void gemm_bt(const u16* __restrict__ A,
                                               const u16* __restrict__ Bt,
                                               void* __restrict__ C,
                                               int M, int N, int K,
                                               const int* __restrict__ flag,
                                               const void* __restrict__ bias,
                                               int kslices) {
    constexpr int BM = 32 * MT, BN = 32 * NT;
    __shared__ __align__(16) u16 As[BM * 32];
    __shared__ __align__(16) u16 Bs[BN * 32];
    const int tid = threadIdx.x;
    const int w = tid >> 6, lane = tid & 63;
    const int wm = w & 1, wn = w >> 1;
    const int m_blk = blockIdx.x * BM, n_blk = blockIdx.y * BN;
    const int lm = lane & 15, lq = lane >> 4;
    const int sr = lane >> 2, sc = (lane & 3) << 3;
    const int f = (OUT_MODE == 2 || OUT_MODE == 4) ? flag[0] : 0;
    const int klen = K / kslices;
    const int kb0 = blockIdx.z * klen;

    f32x4 acc[MT][NT];
#pragma unroll
    for (int i = 0; i < MT; ++i)
#pragma unroll
        for (int j = 0; j < NT; ++j) acc[i][j] = (f32x4){0.f, 0.f, 0.f, 0.f};

    for (int kb = kb0; kb < kb0 + klen; kb += 32) {
        __syncthreads();
#pragma unroll
        for (int i = 0; i < BM / 64; ++i) {
            int row = i * 64 + w * 16;
            gload16(A + (size_t)(m_blk + row + sr) * K + kb + sc, As + row * 32);
        }
#pragma unroll
        for (int i = 0; i < BN / 64; ++i) {
            int row = i * 64 + w * 16;
            gload16(Bt + (size_t)(n_blk + row + sr) * K + kb + sc, Bs + row * 32);
        }
        __syncthreads();

        bf16x8 af[MT], bf[NT];
#pragma unroll
        for (int tm = 0; tm < MT; ++tm)
            af[tm] = *(const bf16x8*)(As + (wm * 16 * MT + tm * 16 + lm) * 32 + lq * 8);
#pragma unroll
        for (int tn = 0; tn < NT; ++tn)
            bf[tn] = *(const bf16x8*)(Bs + (wn * 16 * NT + tn * 16 + lm) * 32 + lq * 8);
#pragma unroll
        for (int tm = 0; tm < MT; ++tm)
#pragma unroll
            for (int tn = 0; tn < NT; ++tn)
                acc[tm][tn] = __builtin_amdgcn_mfma_f32_16x16x32_bf16(af[tm], bf[tn],
                                                                      acc[tm][tn], 0, 0, 0);
    }

#pragma unroll
    for (int tm = 0; tm < MT; ++tm)
#pragma unroll
        for (int tn = 0; tn < NT; ++tn)
#pragma unroll
            for (int r = 0; r < 4; ++r) {
                int row = m_blk + wm * 16 * MT + tm * 16 + lq * 4 + r;
                int col = n_blk + wn * 16 * NT + tn * 16 + lm;
                float v = acc[tm][tn][r];
                if (OUT_MODE == 1) {
                    ((u16*)C)[(size_t)row * N + col] = f2b(v);
                } else if (OUT_MODE == 2) {
                    if (f) ((u16*)C)[(size_t)row * N + col] = f2b(v);
                    else   ((float*)C)[(size_t)row * N + col] = v;
                } else if (OUT_MODE == 4) {
                    float b = rdf(bias, col, f);
                    float t2 = v + b;
                    float sp = fmaxf(t2, 0.f) + __logf(1.f + __expf(-fabsf(t2)));
                    ((float*)C)[(size_t)row * N + col] = sp;
                } else {  // 5: fp32 partial per k-slice
                    ((float*)C)[(size_t)blockIdx.z * M * N + (size_t)row * N + col] = v;
                }
            }
}

// ---------------- reduce 8 k-slice partials -> xdbl fp32 + dtb bf16 ----------------
__global__ __launch_bounds__(256) void reduce_k(const float* __restrict__ parts,
                                                float* __restrict__ xdbl,
                                                u16* __restrict__ dtb) {
    int idx = blockIdx.x * 256 + threadIdx.x;  // over 1024*128
    float s = 0.f;
#pragma unroll
    for (int sl = 0; sl < 8; ++sl) s += parts[sl * 131072 + idx];
    xdbl[idx] = s;
    int col = idx & 127;
    if (col < 64) dtb[(idx >> 7) * 64 + col] = f2b(s);
}

// ---------------- causal depthwise conv (K=4) + SiLU ----------------
__global__ __launch_bounds__(256) void conv_silu_k(const u16* __restrict__ xz,
                                                   const void* __restrict__ cw,
                                                   const void* __restrict__ cb,
                                                   u16* __restrict__ xc,
                                                   const int* __restrict__ flag) {
    int f = *flag;
    int idx = blockIdx.x * 256 + threadIdx.x;  // over 1024*2048
    int t = idx >> 11, d = idx & 2047;
    float acc = rdf(cb, d, f);
#pragma unroll
    for (int k = 0; k < 4; ++k) {
        int tt = t + k - 3;
        if (tt >= 0) acc += b2f(xz[(size_t)tt * 4096 + d]) * rdf(cw, d * 4 + k, f);
    }
    xc[idx] = f2b(acc * fsig(acc));
}

// ---------------- chunked scan, 3 dispatches (C=32, T=32); B/C from xdbl via LDS ----------------
// lane owns 8 n-states of (d, nh); lanes 2k/2k+1 share d; chunk c block-uniform.
__global__ __launch_bounds__(256) void scan1_k(const float* __restrict__ delta,
                                               const u16* __restrict__ xc,
                                               const float* __restrict__ xdbl,
                                               const void* __restrict__ A_log,
                                               float* __restrict__ Acar,
                                               float* __restrict__ Bcar,
                                               const int* __restrict__ flag) {
    __shared__ float BCs[32][32];  // [t_local][col-64]: B(0..15)/C(16..31)
    const int f = *flag;
    const int g = blockIdx.x * 256 + threadIdx.x;  // over 32*4096
    const int c = g >> 12, rem = g & 4095;
    const int d = rem >> 1, nh = rem & 1;
    const int n0 = nh << 3;
    const int t0 = c * 32;
    {
        int idx = threadIdx.x * 4;
        int tl = idx >> 5, col = idx & 31;
        *(f32x4*)&BCs[tl][col] = *(const f32x4*)(xdbl + (t0 + tl) * 128 + 64 + col);
    }
    __syncthreads();

    float A[8], P[8], h[8];
#pragma unroll
    for (int j = 0; j < 8; ++j) {
        A[j] = -__expf(rdf(A_log, d * 16 + n0 + j, f));
        P[j] = 1.f;
        h[j] = 0.f;
    }
#pragma unroll 4
    for (int i = 0; i < 32; ++i) {
        int t = t0 + i;
        float de = delta[t * 2048 + d];
        float dBu = de * b2f(xc[t * 2048 + d]);
        f32x4 Bv0 = *(const f32x4*)&BCs[i][n0];
        f32x4 Bv1 = *(const f32x4*)&BCs[i][n0 + 4];
#pragma unroll
        for (int j = 0; j < 8; ++j) {
            float Bv = (j < 4) ? Bv0[j & 3] : Bv1[j & 3];
            float a = __expf(de * A[j]);
            h[j] = a * h[j] + Bv * dBu;
            P[j] *= a;
        }
    }
    f32x4 pa0 = {P[0], P[1], P[2], P[3]}, pa1 = {P[4], P[5], P[6], P[7]};
    f32x4 hb0 = {h[0], h[1], h[2], h[3]}, hb1 = {h[4], h[5], h[6], h[7]};
    size_t base = (size_t)c * 32768 + d * 16 + n0;
    *(f32x4*)(Acar + base) = pa0;
    *(f32x4*)(Acar + base + 4) = pa1;
    *(f32x4*)(Bcar + base) = hb0;
    *(f32x4*)(Bcar + base + 4) = hb1;
}

__global__ __launch_bounds__(256) void scan2_k(const float* __restrict__ Acar,
                                               float* __restrict__ Bcar) {
    int idx = blockIdx.x * 256 + threadIdx.x;  // over 32768
    float H = 0.f;
    for (int c = 0; c < 32; ++c) {
        float a = Acar[c * 32768 + idx];
        float b = Bcar[c * 32768 + idx];
        Bcar[c * 32768 + idx] = H;
        H = a * H + b;
    }
}

__global__ __launch_bounds__(256) void scan3_k(const float* __restrict__ delta,
                                               const u16* __restrict__ xc,
                                               const float* __restrict__ xdbl,
                                               const u16* __restrict__ xz,
                                               const void* __restrict__ A_log,
                                               const void* __restrict__ Dvp,
                                               const float* __restrict__ Bcar,
                                               u16* __restrict__ yg,
                                               const int* __restrict__ flag) {
    __shared__ float BCs[32][32];
    const int f = *flag;
    const int g = blockIdx.x * 256 + threadIdx.x;  // over 32*4096
    const int c = g >> 12, rem = g & 4095;
    const int d = rem >> 1, nh = rem & 1;
    const int n0 = nh << 3;
    const int t0 = c * 32;
    {
        int idx = threadIdx.x * 4;
        int tl = idx >> 5, col = idx & 31;
        *(f32x4*)&BCs[tl][col] = *(const f32x4*)(xdbl + (t0 + tl) * 128 + 64 + col);
    }
    __syncthreads();

    float A[8], h[8];
    size_t base = (size_t)c * 32768 + d * 16 + n0;
    f32x4 h0 = *(const f32x4*)(Bcar + base);
    f32x4 h1 = *(const f32x4*)(Bcar + base + 4);
#pragma unroll
    for (int j = 0; j < 8; ++j) {
        A[j] = -__expf(rdf(A_log, d * 16 + n0 + j, f));
        h[j] = (j < 4) ? h0[j & 3] : h1[j & 3];
    }
    float Dd = rdf(Dvp, d, f);
#pragma unroll 4
    for (int i = 0; i < 32; ++i) {
        int t = t0 + i;
        float de = delta[t * 2048 + d];
        float u = b2f(xc[t * 2048 + d]);
        float dBu = de * u;
        f32x4 Bv0 = *(const f32x4*)&BCs[i][n0];
        f32x4 Bv1 = *(const f32x4*)&BCs[i][n0 + 4];
        f32x4 Cv0 = *(const f32x4*)&BCs[i][16 + n0];
        f32x4 Cv1 = *(const f32x4*)&BCs[i][20 + n0];
        float p = 0.f;
#pragma unroll
        for (int j = 0; j < 8; ++j) {
            float Bv = (j < 4) ? Bv0[j & 3] : Bv1[j & 3];
            float Cv = (j < 4) ? Cv0[j & 3] : Cv1[j & 3];
            float a = __expf(de * A[j]);
            h[j] = a * h[j] + Bv * dBu;
            p += h[j] * Cv;
        }
        p += __shfl_xor(p, 1);  // combine the two n-halves (lanes 2k,2k+1 share d)
        if (nh == 0) {
            float r = b2f(xz[(size_t)t * 4096 + 2048 + d]);
            float yt = p + u * Dd;
            yg[t * 2048 + d] = f2b(yt * r * fsig(r));
        }
    }
}

// fallback monolithic scan (only if ws too small for carries)
__global__ __launch_bounds__(256) void scan_k(const float* __restrict__ delta,
                                              const u16* __restrict__ xc,
                                              const float* __restrict__ xdbl,
                                              const u16* __restrict__ xz,
                                              const void* __restrict__ A_log,
                                              const void* __restrict__ Dvp,
                                              u16* __restrict__ yg,
                                              const int* __restrict__ flag) {
    int f = *flag;
    int g = blockIdx.x * 256 + threadIdx.x;
    int d = g >> 4, n = g & 15;
    float A = -__expf(rdf(A_log, d * 16 + n, f));
    float Dd = rdf(Dvp, d, f);
    float h = 0.f;
    for (int t = 0; t < LSEQ; ++t) {
        float de = delta[t * 2048 + d];
        float u = b2f(xc[t * 2048 + d]);
        float Bv = xdbl[t * 128 + 64 + n];
        float Cv = xdbl[t * 128 + 80 + n];
        h = __expf(de * A) * h + (de * Bv) * u;
        float p = h * Cv;
        p += __shfl_xor(p, 1);
        p += __shfl_xor(p, 2);
        p += __shfl_xor(p, 4);
        p += __shfl_xor(p, 8);
        if (n == 0) {
            float r = b2f(xz[(size_t)t * 4096 + 2048 + d]);
            float yt = p + u * Dd;
            yg[t * 2048 + d] = f2b(yt * r * fsig(r));
        }
    }
}

extern "C" void kernel_launch(void* const* d_in, const int* in_sizes, int n_in,
                              void* d_out, int out_size, void* d_ws, size_t ws_size,
                              hipStream_t stream) {
    const void* x      = d_in[0];
    const void* W_in   = d_in[1];
    const void* conv_w = d_in[2];
    const void* conv_b = d_in[3];
    const void* W_x    = d_in[4];
    const void* W_dt   = d_in[5];
    const void* b_dt   = d_in[6];
    const void* A_log  = d_in[7];
    const void* Dv     = d_in[8];
    const void* W_out  = d_in[9];

    char* ws = (char*)d_ws;
    u16*   xz     = (u16*)(ws);               // 8388608 -> 8388608
    u16*   xconv  = (u16*)(ws + 8388608);     // 4194304 -> 12582912
    float* parts  = (float*)(ws + 12582912);  // [8,1024,128] fp32 = 4194304 -> 16777216
    float* xdbl   = (float*)(ws + 16777216);  // [1024,128] fp32 = 524288 -> 17301504
    u16*   dtb    = (u16*)(ws + 17301504);    // [1024,64] bf16 = 131072 -> 17432576
    float* delta  = (float*)(ws + 17432576);  // 8388608 -> 25821184
    u16*   W_in_t = (u16*)(ws + 17432576);    // alias: W_in^T [4096,1024], gemm1 only
    u16*   yg     = (u16*)(ws + 25821184);    // 4194304 -> 30015488
    u16*   xb     = (u16*)(ws + 25821184);    // alias: x bf16, gemm1 only
    u16*   W_x_t  = (u16*)(ws + 30015488);    // W_x^T padded [128,2048] = 524288 -> 30539776
    u16*   W_dt_t = (u16*)(ws + 30539776);    // W_dt^T [2048,64] = 262144 -> 30801920
    u16*   W_out_t= (u16*)(ws + 30801920);    // W_out^T [1024,2048] = 4194304 -> 34996224
    int*   flag   = (int*)(ws + 34996224);    // 4 B (pad to 34996352)
    float* Acar   = (float*)(ws + 34996352);  // 4194304 -> 39190656
    float* Bcar   = (float*)(ws + 39190656);  // 4194304 -> 43384960
    const bool chunked_ok = (ws_size >= 43384960);

    // 0) prep: detect + x->bf16 + all weight transposes
    prep_k<<<10624, 256, 0, stream>>>(x, W_in, W_out, W_x, W_dt,
                                      xb, W_in_t, W_out_t, W_x_t, W_dt_t, flag);
    // 1) xz = x @ W_in   [1024,4096] bf16  (128x128 tiles, 256 blocks = 1/CU,
    //    8 ds_read : 16 MFMA per K-iter — best LDS:MFMA ratio under the
    //    global_load_lds stride-32 layout whose 8-way read conflict is structural)
    gemm_bt<4, 4, 1><<<dim3(8, 32), 256, 0, stream>>>(xb, W_in_t, (void*)xz,
                                                      1024, 4096, 1024, flag, nullptr, 1);
    // 2) x_conv = silu(causal_dw_conv(x_in))
    conv_silu_k<<<8192, 256, 0, stream>>>(xz, conv_w, conv_b, xconv, flag);
    // 3) x_dbl partials = x_conv @ W_x^T(padded 128), K split 8 ways (128 blocks)
    gemm_bt<2, 4, 5><<<dim3(16, 1, 8), 256, 0, stream>>>(xconv, W_x_t, (void*)parts,
                                                         1024, 128, 2048, flag, nullptr, 8);
    // 3b) reduce partials -> xdbl fp32 + dtb bf16
    reduce_k<<<512, 256, 0, stream>>>(parts, xdbl, dtb);
    // 4) delta = softplus(dt @ W_dt + b_dt)  (64x128 tiles, 256 blocks)
    gemm_bt<2, 4, 4><<<dim3(16, 16), 256, 0, stream>>>(dtb, W_dt_t, (void*)delta,
                                                       1024, 2048, 64, flag, b_dt, 1);

    // 5) chunked scan, 3 dispatches (grid syncs cost ~100 µs each here — never cooperative)
    if (chunked_ok) {
        scan1_k<<<512, 256, 0, stream>>>(delta, xconv, xdbl, A_log, Acar, Bcar, flag);
        scan2_k<<<128, 256, 0, stream>>>(Acar, Bcar);
        scan3_k<<<512, 256, 0, stream>>>(delta, xconv, xdbl, xz, A_log, Dv, Bcar, yg, flag);
    } else {
        scan_k<<<128, 256, 0, stream>>>(delta, xconv, xdbl, xz, A_log, Dv, yg, flag);
    }

    // 6) out = yg @ W_out   [1024,1024]  (64x128 tiles, 128 blocks, 6 reads : 8 MFMA)
    gemm_bt<2, 4, 2><<<dim3(16, 8), 256, 0, stream>>>(yg, W_out_t, d_out,
                                                      1024, 1024, 2048, flag, nullptr, 1);
}

// Round 12
// 241.193 us; speedup vs baseline: 1.0667x; 1.0667x over previous
//
#include <hip/hip_runtime.h>

typedef unsigned short u16;
typedef unsigned int u32;
typedef __attribute__((ext_vector_type(8))) short bf16x8;
typedef __attribute__((ext_vector_type(4))) float f32x4;

#define LSEQ 1024

__device__ __forceinline__ float b2f(u16 v) { return __uint_as_float(((u32)v) << 16); }
__device__ __forceinline__ u16 f2b(float f) {
    u32 x = __float_as_uint(f);
    return (u16)((x + 0x7fffu + ((x >> 16) & 1u)) >> 16);
}
__device__ __forceinline__ float rdf(const void* p, size_t i, int f) {
    return f ? b2f(((const u16*)p)[i]) : ((const float*)p)[i];
}
__device__ __forceinline__ float fsig(float x) {
    return __builtin_amdgcn_rcpf(1.f + __expf(-x));
}

typedef const __attribute__((address_space(1))) u32* gp_t;
typedef __attribute__((address_space(3))) u32* lp_t;
__device__ __forceinline__ void gload16(const u16* g, u16* lds_wave_base) {
    __builtin_amdgcn_global_load_lds((gp_t)g, (lp_t)lds_wave_base, 16, 0, 0);
}

// ---------------- prep: per-block dtype detect + x->bf16 + all weight transposes ----------------
__global__ __launch_bounds__(256) void prep_k(const void* __restrict__ x,
                                              const void* __restrict__ W_in,
                                              const void* __restrict__ W_out,
                                              const void* __restrict__ W_x,
                                              const void* __restrict__ W_dt,
                                              u16* __restrict__ xb,
                                              u16* __restrict__ W_in_t,
                                              u16* __restrict__ W_out_t,
                                              u16* __restrict__ W_x_t,
                                              u16* __restrict__ W_dt_t,
                                              int* __restrict__ flag) {
    __shared__ int cnt;
    __shared__ u16 tile[32][33];
    if (threadIdx.x == 0) cnt = 0;
    __syncthreads();
    const u16* xu = (const u16*)x;
    int c = 0;
#pragma unroll
    for (int j = 0; j < 8; ++j) {
        u16 u = xu[threadIdx.x * 8 + j];
        int e = (u >> 7) & 0xFF;
        c += (e == 0 || (e >= 100 && e <= 140)) ? 1 : 0;
    }
    atomicAdd(&cnt, c);
    __syncthreads();
    const int f = (cnt >= 1638) ? 1 : 0;
    if (blockIdx.x == 0 && threadIdx.x == 0) *flag = f;

    int blk = blockIdx.x;
    if (blk < 4096) {  // x -> bf16
        int i = blk * 256 + threadIdx.x;
        xb[i] = f ? xu[i] : f2b(((const float*)x)[i]);
        return;
    }
    blk -= 4096;
    // weight transposes: dst[Cp,R] = src[R,Cn]^T (zero-padded rows >= Cn)
    const void* src; u16* dst; int R, Cn, nbc, t;
    if (blk < 4096)      { src = W_in;  dst = W_in_t;  R = 1024; Cn = 4096; nbc = 128; t = blk; }
    else if (blk < 6144) { src = W_out; dst = W_out_t; R = 2048; Cn = 1024; nbc = 32;  t = blk - 4096; }
    else if (blk < 6400) { src = W_x;   dst = W_x_t;   R = 2048; Cn = 96;   nbc = 4;   t = blk - 6144; }
    else                 { src = W_dt;  dst = W_dt_t;  R = 64;   Cn = 2048; nbc = 64;  t = blk - 6400; }
    int br = t / nbc, bc = t - br * nbc;
    int r0 = br * 32, c0 = bc * 32;
    int tx = threadIdx.x & 31, ty0 = threadIdx.x >> 5;
#pragma unroll
    for (int p = 0; p < 4; ++p) {
        int ty = ty0 + p * 8;
        float v = (c0 + tx < Cn) ? rdf(src, (size_t)(r0 + ty) * Cn + c0 + tx, f) : 0.f;
        tile[ty][tx] = f2b(v);
    }
    __syncthreads();
#pragma unroll
    for (int p = 0; p < 4; ++p) {
        int ty = ty0 + p * 8;
        dst[(size_t)(c0 + ty) * R + r0 + tx] = tile[tx][ty];
    }
}

// ---------------- GEMM, B transposed: C[M,N] = A[M,K] * Bt[N,K]^T ----------------
// OUT_MODE: 1=bf16, 2=dual(flag), 4=softplus(v+bias[col]) fp32,
//           5=fp32 partial at C + blockIdx.z*M*N (K split into kslices)
template <int MT, int NT, int OUT_MODE>
__global__ __launch_bounds__(256) void gemm_bt(const u16* __restrict__ A,
                                               const u16* __restrict__ Bt,
                                               void* __restrict__ C,
                                               int M, int N, int K,
                                               const int* __restrict__ flag,
                                               const void* __restrict__ bias,
                                               int kslices) {
    constexpr int BM = 32 * MT, BN = 32 * NT;
    __shared__ __align__(16) u16 As[BM * 32];
    __shared__ __align__(16) u16 Bs[BN * 32];
    const int tid = threadIdx.x;
    const int w = tid >> 6, lane = tid & 63;
    const int wm = w & 1, wn = w >> 1;
    const int m_blk = blockIdx.x * BM, n_blk = blockIdx.y * BN;
    const int lm = lane & 15, lq = lane >> 4;
    const int sr = lane >> 2, sc = (lane & 3) << 3;
    const int f = (OUT_MODE == 2 || OUT_MODE == 4) ? flag[0] : 0;
    const int klen = K / kslices;
    const int kb0 = blockIdx.z * klen;

    f32x4 acc[MT][NT];
#pragma unroll
    for (int i = 0; i < MT; ++i)
#pragma unroll
        for (int j = 0; j < NT; ++j) acc[i][j] = (f32x4){0.f, 0.f, 0.f, 0.f};

    for (int kb = kb0; kb < kb0 + klen; kb += 32) {
        __syncthreads();
#pragma unroll
        for (int i = 0; i < BM / 64; ++i) {
            int row = i * 64 + w * 16;
            gload16(A + (size_t)(m_blk + row + sr) * K + kb + sc, As + row * 32);
        }
#pragma unroll
        for (int i = 0; i < BN / 64; ++i) {
            int row = i * 64 + w * 16;
            gload16(Bt + (size_t)(n_blk + row + sr) * K + kb + sc, Bs + row * 32);
        }
        __syncthreads();

        bf16x8 af[MT], bf[NT];
#pragma unroll
        for (int tm = 0; tm < MT; ++tm)
            af[tm] = *(const bf16x8*)(As + (wm * 16 * MT + tm * 16 + lm) * 32 + lq * 8);
#pragma unroll
        for (int tn = 0; tn < NT; ++tn)
            bf[tn] = *(const bf16x8*)(Bs + (wn * 16 * NT + tn * 16 + lm) * 32 + lq * 8);
#pragma unroll
        for (int tm = 0; tm < MT; ++tm)
#pragma unroll
            for (int tn = 0; tn < NT; ++tn)
                acc[tm][tn] = __builtin_amdgcn_mfma_f32_16x16x32_bf16(af[tm], bf[tn],
                                                                      acc[tm][tn], 0, 0, 0);
    }

#pragma unroll
    for (int tm = 0; tm < MT; ++tm)
#pragma unroll
        for (int tn = 0; tn < NT; ++tn)
#pragma unroll
            for (int r = 0; r < 4; ++r) {
                int row = m_blk + wm * 16 * MT + tm * 16 + lq * 4 + r;
                int col = n_blk + wn * 16 * NT + tn * 16 + lm;
                float v = acc[tm][tn][r];
                if (OUT_MODE == 1) {
                    ((u16*)C)[(size_t)row * N + col] = f2b(v);
                } else if (OUT_MODE == 2) {
                    if (f) ((u16*)C)[(size_t)row * N + col] = f2b(v);
                    else   ((float*)C)[(size_t)row * N + col] = v;
                } else if (OUT_MODE == 4) {
                    float b = rdf(bias, col, f);
                    float t2 = v + b;
                    float sp = fmaxf(t2, 0.f) + __logf(1.f + __expf(-fabsf(t2)));
                    ((float*)C)[(size_t)row * N + col] = sp;
                } else {  // 5: fp32 partial per k-slice
                    ((float*)C)[(size_t)blockIdx.z * M * N + (size_t)row * N + col] = v;
                }
            }
}

// ---------------- reduce 8 k-slice partials -> xdbl fp32 + dtb bf16 ----------------
__global__ __launch_bounds__(256) void reduce_k(const float* __restrict__ parts,
                                                float* __restrict__ xdbl,
                                                u16* __restrict__ dtb) {
    int idx = blockIdx.x * 256 + threadIdx.x;  // over 1024*128
    float s = 0.f;
#pragma unroll
    for (int sl = 0; sl < 8; ++sl) s += parts[sl * 131072 + idx];
    xdbl[idx] = s;
    int col = idx & 127;
    if (col < 64) dtb[(idx >> 7) * 64 + col] = f2b(s);
}

// ---------------- causal depthwise conv (K=4) + SiLU ----------------
__global__ __launch_bounds__(256) void conv_silu_k(const u16* __restrict__ xz,
                                                   const void* __restrict__ cw,
                                                   const void* __restrict__ cb,
                                                   u16* __restrict__ xc,
                                                   const int* __restrict__ flag) {
    int f = *flag;
    int idx = blockIdx.x * 256 + threadIdx.x;  // over 1024*2048
    int t = idx >> 11, d = idx & 2047;
    float acc = rdf(cb, d, f);
#pragma unroll
    for (int k = 0; k < 4; ++k) {
        int tt = t + k - 3;
        if (tt >= 0) acc += b2f(xz[(size_t)tt * 4096 + d]) * rdf(cw, d * 4 + k, f);
    }
    xc[idx] = f2b(acc * fsig(acc));
}

// ---------------- chunked scan, 3 dispatches (C=32, T=32); B/C from xdbl via LDS ----------------
// lane owns 8 n-states of (d, nh); lanes 2k/2k+1 share d; chunk c block-uniform.
__global__ __launch_bounds__(256) void scan1_k(const float* __restrict__ delta,
                                               const u16* __restrict__ xc,
                                               const float* __restrict__ xdbl,
                                               const void* __restrict__ A_log,
                                               float* __restrict__ Acar,
                                               float* __restrict__ Bcar,
                                               const int* __restrict__ flag) {
    __shared__ float BCs[32][32];  // [t_local][col-64]: B(0..15)/C(16..31)
    const int f = *flag;
    const int g = blockIdx.x * 256 + threadIdx.x;  // over 32*4096
    const int c = g >> 12, rem = g & 4095;
    const int d = rem >> 1, nh = rem & 1;
    const int n0 = nh << 3;
    const int t0 = c * 32;
    {
        int idx = threadIdx.x * 4;
        int tl = idx >> 5, col = idx & 31;
        *(f32x4*)&BCs[tl][col] = *(const f32x4*)(xdbl + (t0 + tl) * 128 + 64 + col);
    }
    __syncthreads();

    float A[8], P[8], h[8];
#pragma unroll
    for (int j = 0; j < 8; ++j) {
        A[j] = -__expf(rdf(A_log, d * 16 + n0 + j, f));
        P[j] = 1.f;
        h[j] = 0.f;
    }
#pragma unroll 4
    for (int i = 0; i < 32; ++i) {
        int t = t0 + i;
        float de = delta[t * 2048 + d];
        float dBu = de * b2f(xc[t * 2048 + d]);
        f32x4 Bv0 = *(const f32x4*)&BCs[i][n0];
        f32x4 Bv1 = *(const f32x4*)&BCs[i][n0 + 4];
#pragma unroll
        for (int j = 0; j < 8; ++j) {
            float Bv = (j < 4) ? Bv0[j & 3] : Bv1[j & 3];
            float a = __expf(de * A[j]);
            h[j] = a * h[j] + Bv * dBu;
            P[j] *= a;
        }
    }
    f32x4 pa0 = {P[0], P[1], P[2], P[3]}, pa1 = {P[4], P[5], P[6], P[7]};
    f32x4 hb0 = {h[0], h[1], h[2], h[3]}, hb1 = {h[4], h[5], h[6], h[7]};
    size_t base = (size_t)c * 32768 + d * 16 + n0;
    *(f32x4*)(Acar + base) = pa0;
    *(f32x4*)(Acar + base + 4) = pa1;
    *(f32x4*)(Bcar + base) = hb0;
    *(f32x4*)(Bcar + base + 4) = hb1;
}

__global__ __launch_bounds__(256) void scan2_k(const float* __restrict__ Acar,
                                               float* __restrict__ Bcar) {
    int idx = blockIdx.x * 256 + threadIdx.x;  // over 32768
    float H = 0.f;
    for (int c = 0; c < 32; ++c) {
        float a = Acar[c * 32768 + idx];
        float b = Bcar[c * 32768 + idx];
        Bcar[c * 32768 + idx] = H;
        H = a * H + b;
    }
}

__global__ __launch_bounds__(256) void scan3_k(const float* __restrict__ delta,
                                               const u16* __restrict__ xc,
                                               const float* __restrict__ xdbl,
                                               const u16* __restrict__ xz,
                                               const void* __restrict__ A_log,
                                               const void* __restrict__ Dvp,
                                               const float* __restrict__ Bcar,
                                               u16* __restrict__ yg,
                                               const int* __restrict__ flag) {
    __shared__ float BCs[32][32];
    const int f = *flag;
    const int g = blockIdx.x * 256 + threadIdx.x;  // over 32*4096
    const int c = g >> 12, rem = g & 4095;
    const int d = rem >> 1, nh = rem & 1;
    const int n0 = nh << 3;
    const int t0 = c * 32;
    {
        int idx = threadIdx.x * 4;
        int tl = idx >> 5, col = idx & 31;
        *(f32x4*)&BCs[tl][col] = *(const f32x4*)(xdbl + (t0 + tl) * 128 + 64 + col);
    }
    __syncthreads();

    float A[8], h[8];
    size_t base = (size_t)c * 32768 + d * 16 + n0;
    f32x4 h0 = *(const f32x4*)(Bcar + base);
    f32x4 h1 = *(const f32x4*)(Bcar + base + 4);
#pragma unroll
    for (int j = 0; j < 8; ++j) {
        A[j] = -__expf(rdf(A_log, d * 16 + n0 + j, f));
        h[j] = (j < 4) ? h0[j & 3] : h1[j & 3];
    }
    float Dd = rdf(Dvp, d, f);
#pragma unroll 4
    for (int i = 0; i < 32; ++i) {
        int t = t0 + i;
        float de = delta[t * 2048 + d];
        float u = b2f(xc[t * 2048 + d]);
        float dBu = de * u;
        f32x4 Bv0 = *(const f32x4*)&BCs[i][n0];
        f32x4 Bv1 = *(const f32x4*)&BCs[i][n0 + 4];
        f32x4 Cv0 = *(const f32x4*)&BCs[i][16 + n0];
        f32x4 Cv1 = *(const f32x4*)&BCs[i][20 + n0];
        float p = 0.f;
#pragma unroll
        for (int j = 0; j < 8; ++j) {
            float Bv = (j < 4) ? Bv0[j & 3] : Bv1[j & 3];
            float Cv = (j < 4) ? Cv0[j & 3] : Cv1[j & 3];
            float a = __expf(de * A[j]);
            h[j] = a * h[j] + Bv * dBu;
            p += h[j] * Cv;
        }
        p += __shfl_xor(p, 1);  // combine the two n-halves (lanes 2k,2k+1 share d)
        if (nh == 0) {
            float r = b2f(xz[(size_t)t * 4096 + 2048 + d]);
            float yt = p + u * Dd;
            yg[t * 2048 + d] = f2b(yt * r * fsig(r));
        }
    }
}

// fallback monolithic scan (only if ws too small for carries)
__global__ __launch_bounds__(256) void scan_k(const float* __restrict__ delta,
                                              const u16* __restrict__ xc,
                                              const float* __restrict__ xdbl,
                                              const u16* __restrict__ xz,
                                              const void* __restrict__ A_log,
                                              const void* __restrict__ Dvp,
                                              u16* __restrict__ yg,
                                              const int* __restrict__ flag) {
    int f = *flag;
    int g = blockIdx.x * 256 + threadIdx.x;
    int d = g >> 4, n = g & 15;
    float A = -__expf(rdf(A_log, d * 16 + n, f));
    float Dd = rdf(Dvp, d, f);
    float h = 0.f;
    for (int t = 0; t < LSEQ; ++t) {
        float de = delta[t * 2048 + d];
        float u = b2f(xc[t * 2048 + d]);
        float Bv = xdbl[t * 128 + 64 + n];
        float Cv = xdbl[t * 128 + 80 + n];
        h = __expf(de * A) * h + (de * Bv) * u;
        float p = h * Cv;
        p += __shfl_xor(p, 1);
        p += __shfl_xor(p, 2);
        p += __shfl_xor(p, 4);
        p += __shfl_xor(p, 8);
        if (n == 0) {
            float r = b2f(xz[(size_t)t * 4096 + 2048 + d]);
            float yt = p + u * Dd;
            yg[t * 2048 + d] = f2b(yt * r * fsig(r));
        }
    }
}

extern "C" void kernel_launch(void* const* d_in, const int* in_sizes, int n_in,
                              void* d_out, int out_size, void* d_ws, size_t ws_size,
                              hipStream_t stream) {
    const void* x      = d_in[0];
    const void* W_in   = d_in[1];
    const void* conv_w = d_in[2];
    const void* conv_b = d_in[3];
    const void* W_x    = d_in[4];
    const void* W_dt   = d_in[5];
    const void* b_dt   = d_in[6];
    const void* A_log  = d_in[7];
    const void* Dv     = d_in[8];
    const void* W_out  = d_in[9];

    char* ws = (char*)d_ws;
    u16*   xz     = (u16*)(ws);               // 8388608 -> 8388608
    u16*   xconv  = (u16*)(ws + 8388608);     // 4194304 -> 12582912
    float* parts  = (float*)(ws + 12582912);  // [8,1024,128] fp32 = 4194304 -> 16777216
    float* xdbl   = (float*)(ws + 16777216);  // [1024,128] fp32 = 524288 -> 17301504
    u16*   dtb    = (u16*)(ws + 17301504);    // [1024,64] bf16 = 131072 -> 17432576
    float* delta  = (float*)(ws + 17432576);  // 8388608 -> 25821184
    u16*   W_in_t = (u16*)(ws + 17432576);    // alias: W_in^T [4096,1024], gemm1 only
    u16*   yg     = (u16*)(ws + 25821184);    // 4194304 -> 30015488
    u16*   xb     = (u16*)(ws + 25821184);    // alias: x bf16, gemm1 only
    u16*   W_x_t  = (u16*)(ws + 30015488);    // W_x^T padded [128,2048] = 524288 -> 30539776
    u16*   W_dt_t = (u16*)(ws + 30539776);    // W_dt^T [2048,64] = 262144 -> 30801920
    u16*   W_out_t= (u16*)(ws + 30801920);    // W_out^T [1024,2048] = 4194304 -> 34996224
    int*   flag   = (int*)(ws + 34996224);    // 4 B (pad to 34996352)
    float* Acar   = (float*)(ws + 34996352);  // 4194304 -> 39190656
    float* Bcar   = (float*)(ws + 39190656);  // 4194304 -> 43384960
    const bool chunked_ok = (ws_size >= 43384960);

    // 0) prep: detect + x->bf16 + all weight transposes
    prep_k<<<10624, 256, 0, stream>>>(x, W_in, W_out, W_x, W_dt,
                                      xb, W_in_t, W_out_t, W_x_t, W_dt_t, flag);
    // 1) xz = x @ W_in   [1024,4096] bf16  (64x128 tiles, 512 blocks = 2/CU —
    //    measured: beats 128x128/256-block by ~5 µs at this M; parallelism > ratio here)
    gemm_bt<2, 4, 1><<<dim3(16, 32), 256, 0, stream>>>(xb, W_in_t, (void*)xz,
                                                       1024, 4096, 1024, flag, nullptr, 1);
    // 2) x_conv = silu(causal_dw_conv(x_in))
    conv_silu_k<<<8192, 256, 0, stream>>>(xz, conv_w, conv_b, xconv, flag);
    // 3) x_dbl partials = x_conv @ W_x^T(padded 128), K split 8 ways (128 blocks)
    gemm_bt<2, 4, 5><<<dim3(16, 1, 8), 256, 0, stream>>>(xconv, W_x_t, (void*)parts,
                                                         1024, 128, 2048, flag, nullptr, 8);
    // 3b) reduce partials -> xdbl fp32 + dtb bf16
    reduce_k<<<512, 256, 0, stream>>>(parts, xdbl, dtb);
    // 4) delta = softplus(dt @ W_dt + b_dt)  (64x64 tiles, 512 blocks = 2/CU)
    gemm_bt<2, 2, 4><<<dim3(16, 32), 256, 0, stream>>>(dtb, W_dt_t, (void*)delta,
                                                       1024, 2048, 64, flag, b_dt, 1);

    // 5) chunked scan, 3 dispatches (grid syncs cost ~100 µs each here — never cooperative)
    if (chunked_ok) {
        scan1_k<<<512, 256, 0, stream>>>(delta, xconv, xdbl, A_log, Acar, Bcar, flag);
        scan2_k<<<128, 256, 0, stream>>>(Acar, Bcar);
        scan3_k<<<512, 256, 0, stream>>>(delta, xconv, xdbl, xz, A_log, Dv, Bcar, yg, flag);
    } else {
        scan_k<<<128, 256, 0, stream>>>(delta, xconv, xdbl, xz, A_log, Dv, yg, flag);
    }

    // 6) out = yg @ W_out   [1024,1024]  (64x64 tiles, 256 blocks — measured best)
    gemm_bt<2, 2, 2><<<dim3(16, 16), 256, 0, stream>>>(yg, W_out_t, d_out,
                                                       1024, 1024, 2048, flag, nullptr, 1);
}